// Round 9
// baseline (220.480 us; speedup 1.0000x reference)
//
#include <hip/hip_runtime.h>
#include <hip/hip_bf16.h>
#include <math.h>

#define DD 128
#define SS 1024
#define NROWS 8192
#define EPSF 1e-7f
#define LN_EPSF 1e-3f
#define TCUT 30.0f

typedef __attribute__((ext_vector_type(8))) short bf16x8;
typedef __attribute__((ext_vector_type(4))) float f32x4;
typedef __attribute__((ext_vector_type(16))) float f32x16;

__device__ __forceinline__ void gload_lds16(const void* g, void* l) {
    __builtin_amdgcn_global_load_lds(
        (const __attribute__((address_space(1))) unsigned int*)g,
        (__attribute__((address_space(3))) unsigned int*)l, 16, 0, 0);
}
__device__ __forceinline__ short f2bf(float v) {
    union { __hip_bfloat16 h; short s; } u;
    u.h = __float2bfloat16(v);
    return u.s;
}
__device__ __forceinline__ float bf2f(short s) {
    union { __hip_bfloat16 h; short s; } u; u.s = s;
    return __bfloat162float(u.h);
}

// ---- K0a: emb -> bf16 fragment-linear: embh3[(d*4+js)*4096 + (ks*64+l)*8+e]
//      = emb[d][js*32 + (l&31)][ks*16 + (l>>5)*8 + e]
__global__ __launch_bounds__(256) void k0a_emb(const float* __restrict__ emb,
                                               short* __restrict__ embh3) {
    __shared__ float lt[32][128];
    int d = blockIdx.x, js = blockIdx.y, t = threadIdx.x;
    {
        int jl = t >> 3, k0 = (t & 7) * 16;
        const float4* src = (const float4*)(emb + (size_t)d * 16384
                                            + (size_t)(js * 32 + jl) * 128 + k0);
#pragma unroll
        for (int q = 0; q < 4; ++q) *(float4*)&lt[jl][k0 + q * 4] = src[q];
    }
    __syncthreads();
    int ks = t >> 5, l0 = (t & 31) * 2;
    union { bf16x8 v[2]; short s[16]; } ob;
#pragma unroll
    for (int li = 0; li < 2; ++li) {
        int l = l0 + li;
        const float* p = &lt[l & 31][ks * 16 + (l >> 5) * 8];
#pragma unroll
        for (int e = 0; e < 8; ++e) ob.s[li * 8 + e] = f2bf(p[e]);
    }
    short* dst = embh3 + (size_t)(d * 4 + js) * 4096 + (size_t)t * 16;
    *(bf16x8*)dst = ob.v[0];
    *(bf16x8*)(dst + 8) = ob.v[1];
}

// ---- K0w: split Wq|Wm into bf16 hi/lo fragment-linear for k1 --------------
__global__ __launch_bounds__(256) void k0w_split(const float* __restrict__ Wq,
        const float* __restrict__ Wm, short* __restrict__ Wfrag) {
    int T = blockIdx.x * 256 + threadIdx.x;       // 65536 total
    int e = T & 7, l = (T >> 3) & 63, ks = (T >> 9) & 3, nt = (T >> 11) & 7,
        mat = (T >> 14) & 1;
    int k = ks * 32 + ((l >> 4) & 3) * 8 + e;
    int c = nt * 16 + (l & 15);
    float v = (mat ? Wm : Wq)[k * 128 + c];
    short h = f2bf(v);
    float lo = v - bf2f(h);
    Wfrag[((((size_t)(mat * 2 + 0) * 8 + nt) * 4 + ks) * 64 + l) * 8 + e] = h;
    Wfrag[((((size_t)(mat * 2 + 1) * 8 + nt) * 4 + ks) * 64 + l) * 8 + e] = f2bf(lo);
}

// ---- K0c: x -> xh2/xl2 (frag-linear for k1) + w,c scalars ------------------
__global__ __launch_bounds__(256) void k0c_xsplit(const float* __restrict__ x,
        const float* __restrict__ Ww, const float* __restrict__ bw,
        const float* __restrict__ Wc, const float* __restrict__ bc,
        short* __restrict__ xh2, short* __restrict__ xl2,
        float* __restrict__ scal) {
    __shared__ float xs[32][129];
    int rb = blockIdx.x, t = threadIdx.x;
    {
        int r = t >> 3, d0 = (t & 7) * 16;
        const float4* src = (const float4*)(x + (size_t)(rb * 32 + r) * 128 + d0);
#pragma unroll
        for (int q = 0; q < 4; ++q) *(float4*)&xs[r][d0 + q * 4] = src[q];
    }
    __syncthreads();
    int ks = (t >> 5) & 3, rf = t >> 7, l0 = (t & 31) * 2;
    union { bf16x8 v[2]; short s[16]; } hb, lb;
#pragma unroll
    for (int li = 0; li < 2; ++li) {
        int l = l0 + li;
        const float* p = &xs[rf * 16 + (l & 15)][ks * 32 + ((l >> 4) & 3) * 8];
#pragma unroll
        for (int e = 0; e < 8; ++e) {
            float v = p[e];
            short h = f2bf(v);
            hb.s[li * 8 + e] = h;
            lb.s[li * 8 + e] = f2bf(v - bf2f(h));
        }
    }
    {
        short* d1 = xh2 + (size_t)rb * 4096 + (size_t)t * 16;
        short* d2 = xl2 + (size_t)rb * 4096 + (size_t)t * 16;
        *(bf16x8*)d1 = hb.v[0]; *(bf16x8*)(d1 + 8) = hb.v[1];
        *(bf16x8*)d2 = lb.v[0]; *(bf16x8*)(d2 + 8) = lb.v[1];
    }
    // w, c scalars
    int rr = t >> 3, seg = t & 7;
    float pw = 0.f, pc = 0.f;
#pragma unroll
    for (int dq = 0; dq < 16; ++dq) {
        float xv = xs[rr][seg * 16 + dq];
        pw = fmaf(xv, Ww[seg * 16 + dq], pw);
        pc = fmaf(xv, Wc[seg * 16 + dq], pc);
    }
    pw += __shfl_xor(pw, 1); pw += __shfl_xor(pw, 2); pw += __shfl_xor(pw, 4);
    pc += __shfl_xor(pc, 1); pc += __shfl_xor(pc, 2); pc += __shfl_xor(pc, 4);
    if (seg == 0) {
        scal[(size_t)(rb * 32 + rr) * 4 + 0] = fmaxf(pw + bw[0], 0.f);
        scal[(size_t)(rb * 32 + rr) * 4 + 1] = fmaxf(pc + bc[0], 0.f);
    }
}

// ---- K1: q'/m via split-bf16 MFMA (3 products each), fused epilogue --------
__global__ __launch_bounds__(256) void k1_mfma(
    const short* __restrict__ xh2, const short* __restrict__ xl2,
    const short* __restrict__ Wfrag,
    const float* __restrict__ bq, const float* __restrict__ bm,
    float* __restrict__ mq, float* __restrict__ mo, float* __restrict__ scal)
{
    __shared__ __align__(16) short wl[65536];   // 128 KB
    __shared__ float red[32][4][2];
    int t = threadIdx.x, w = t >> 6, l = t & 63;
    int l15 = l & 15, g = l >> 4;
    int row0 = blockIdx.x * 32;
#pragma unroll
    for (int it = 0; it < 32; ++it)
        gload_lds16(Wfrag + (size_t)(it * 256 + t) * 8, wl + (size_t)(it * 256 + w * 64) * 8);
    const short* xb  = xh2 + (size_t)blockIdx.x * 4096;
    const short* xlb = xl2 + (size_t)blockIdx.x * 4096;
    bf16x8 Ah[2][4], Al[2][4];
#pragma unroll
    for (int rf = 0; rf < 2; ++rf)
#pragma unroll
        for (int ks = 0; ks < 4; ++ks) {
            size_t o = ((size_t)(rf * 4 + ks) * 64 + l) * 8;
            Ah[rf][ks] = *(const bf16x8*)(xb + o);
            Al[rf][ks] = *(const bf16x8*)(xlb + o);
        }
    __syncthreads();
    f32x4 accq[2][2] = {}, accm[2][2] = {};
#pragma unroll
    for (int ntp = 0; ntp < 2; ++ntp) {
        int nt = w * 2 + ntp;
#pragma unroll
        for (int ks = 0; ks < 4; ++ks) {
            bf16x8 bhq = *(const bf16x8*)(wl + ((size_t)(0  + nt) * 4 + ks) * 512 + l * 8);
            bf16x8 blq = *(const bf16x8*)(wl + ((size_t)(8  + nt) * 4 + ks) * 512 + l * 8);
            bf16x8 bhm = *(const bf16x8*)(wl + ((size_t)(16 + nt) * 4 + ks) * 512 + l * 8);
            bf16x8 blm = *(const bf16x8*)(wl + ((size_t)(24 + nt) * 4 + ks) * 512 + l * 8);
#pragma unroll
            for (int rf = 0; rf < 2; ++rf) {
                accq[rf][ntp] = __builtin_amdgcn_mfma_f32_16x16x32_bf16(Ah[rf][ks], bhq, accq[rf][ntp], 0, 0, 0);
                accq[rf][ntp] = __builtin_amdgcn_mfma_f32_16x16x32_bf16(Ah[rf][ks], blq, accq[rf][ntp], 0, 0, 0);
                accq[rf][ntp] = __builtin_amdgcn_mfma_f32_16x16x32_bf16(Al[rf][ks], bhq, accq[rf][ntp], 0, 0, 0);
                accm[rf][ntp] = __builtin_amdgcn_mfma_f32_16x16x32_bf16(Ah[rf][ks], bhm, accm[rf][ntp], 0, 0, 0);
                accm[rf][ntp] = __builtin_amdgcn_mfma_f32_16x16x32_bf16(Ah[rf][ks], blm, accm[rf][ntp], 0, 0, 0);
                accm[rf][ntp] = __builtin_amdgcn_mfma_f32_16x16x32_bf16(Al[rf][ks], bhm, accm[rf][ntp], 0, 0, 0);
            }
        }
    }
    float sq1[2][4] = {{0,0,0,0},{0,0,0,0}};
    float sq2[2][4] = {{0,0,0,0},{0,0,0,0}};
#pragma unroll
    for (int ntp = 0; ntp < 2; ++ntp) {
        int c = (w * 2 + ntp) * 16 + l15;
        float bqv = bq[c] + EPSF, bmv = bm[c];
#pragma unroll
        for (int rf = 0; rf < 2; ++rf)
#pragma unroll
            for (int reg = 0; reg < 4; ++reg) {
                int rloc = rf * 16 + g * 4 + reg;
                float qp = accq[rf][ntp][reg] + bqv;
                float mv = 1.0f / (1.0f + expf(-(accm[rf][ntp][reg] + bmv)));
                size_t o = (size_t)(row0 + rloc) * 128 + c;
                mq[o] = mv * qp;
                mo[o] = mv;
                sq1[rf][reg] += qp;
                sq2[rf][reg] += qp * qp;
            }
    }
#pragma unroll
    for (int rf = 0; rf < 2; ++rf)
#pragma unroll
        for (int reg = 0; reg < 4; ++reg) {
            float a = sq1[rf][reg], b = sq2[rf][reg];
            a += __shfl_xor(a, 1); a += __shfl_xor(a, 2);
            a += __shfl_xor(a, 4); a += __shfl_xor(a, 8);
            b += __shfl_xor(b, 1); b += __shfl_xor(b, 2);
            b += __shfl_xor(b, 4); b += __shfl_xor(b, 8);
            if (l15 == 0) {
                red[rf * 16 + g * 4 + reg][w][0] = a;
                red[rf * 16 + g * 4 + reg][w][1] = b;
            }
        }
    __syncthreads();
    if (t < 32) {
        float a = red[t][0][0] + red[t][1][0] + red[t][2][0] + red[t][3][0];
        float b = red[t][0][1] + red[t][1][1] + red[t][2][1] + red[t][3][1];
        scal[(size_t)(row0 + t) * 4 + 2] = a;
        scal[(size_t)(row0 + t) * 4 + 3] = sqrtf(b);
    }
}

// ---- K2: windowed pair loop -> qrh2. One row/block; 4 waves x 4 groups of
//      16 lanes = 16 dists per iteration; lane owns 8 d-elements.
__global__ __launch_bounds__(256) void k2_qr(
    const float* __restrict__ x,
    const float* __restrict__ mq, const float* __restrict__ mo,
    const float* __restrict__ scal, short* __restrict__ qrh2)
{
    int row = blockIdx.x;
    int i = row & (SS - 1);
    const float* xb = x + (size_t)(row - i) * DD;
    int t = threadIdx.x, w = t >> 6, l = t & 63;
    int sub = l >> 4, q = l & 15;
    int qo = q * 8;

    float mqv[8], mov[8];
    {
        const float* mp = mq + (size_t)row * DD + qo;
        float4 a = *(const float4*)mp, b = *(const float4*)(mp + 4);
        mqv[0] = a.x; mqv[1] = a.y; mqv[2] = a.z; mqv[3] = a.w;
        mqv[4] = b.x; mqv[5] = b.y; mqv[6] = b.z; mqv[7] = b.w;
        const float* op = mo + (size_t)row * DD + qo;
        float4 c = *(const float4*)op, d = *(const float4*)(op + 4);
        mov[0] = c.x; mov[1] = c.y; mov[2] = c.z; mov[3] = c.w;
        mov[4] = d.x; mov[5] = d.y; mov[6] = d.z; mov[7] = d.w;
    }
    float wv = scal[row * 4 + 0], cv = scal[row * 4 + 1];
    float sumqp = scal[row * 4 + 2], nb = scal[row * 4 + 3];
    float wi = wv + EPSF;
    float dmaxf = cv + TCUT * wi;
    int dmax = (dmaxf >= (float)i) ? i : (int)dmaxf;

    float acc[8] = {0.f, 0.f, 0.f, 0.f, 0.f, 0.f, 0.f, 0.f};
    int nit = (dmax + 15) >> 4;
    int dbase = 1 + w * 4 + sub;
    for (int it = 0; it < nit; ++it) {
        int dist = dbase + it * 16;
        float xv[8];
        if (dist <= dmax) {
            const float* xp = xb + (size_t)(i - dist) * DD + qo;
            float4 a = *(const float4*)xp, b = *(const float4*)(xp + 4);
            xv[0] = a.x; xv[1] = a.y; xv[2] = a.z; xv[3] = a.w;
            xv[4] = b.x; xv[5] = b.y; xv[6] = b.z; xv[7] = b.w;
        } else {
#pragma unroll
            for (int e = 0; e < 8; ++e) xv[e] = 0.f;
        }
        float t1 = 0.f, s1 = 0.f, s2 = 0.f;
#pragma unroll
        for (int e = 0; e < 8; ++e) {
            float xm = xv[e] * mov[e];
            t1 = fmaf(xv[e], mqv[e], t1);
            s1 += xm;
            s2 = fmaf(xm, xm, s2);
        }
#pragma unroll
        for (int off = 1; off < 16; off <<= 1) {
            t1 += __shfl_xor(t1, off);
            s1 += __shfl_xor(s1, off);
            s2 += __shfl_xor(s2, off);
        }
        float tt = ((float)dist - cv) / wi;
        float pe = 1.0f / coshf(tt);
        float dotv = fmaf(pe, t1, EPSF * sumqp);
        float na = sqrtf(fmaf(pe * pe, s2,
                         fmaf(2.0f * EPSF * pe, s1, (float)DD * EPSF * EPSF)));
        float cosv = fminf(1.0f, fmaxf(-1.0f, dotv / (na * nb)));
        float ang = acosf(cosv);
        float wgt = pe * ang;
#pragma unroll
        for (int e = 0; e < 8; ++e) acc[e] = fmaf(wgt, xv[e], acc[e]);
    }
#pragma unroll
    for (int e = 0; e < 8; ++e) {
        acc[e] += __shfl_xor(acc[e], 16);
        acc[e] += __shfl_xor(acc[e], 32);
    }
    __shared__ float sq[4][DD];
    if (l < 16) {
#pragma unroll
        for (int e = 0; e < 8; ++e) sq[w][qo + e] = acc[e];
    }
    __syncthreads();
    if (t < DD) {
        float v = sq[0][t] + sq[1][t] + sq[2][t] + sq[3][t];
        int rbq = row >> 7, rr = row & 127, rt2 = rr >> 5, lp = rr & 31;
        int k = t;
        qrh2[(((size_t)(rbq * 4 + rt2) * 8 + (k >> 4)) * 64
              + (lp + 32 * ((k >> 3) & 1))) * 8 + (k & 7)] = f2bf(v);
    }
}

// ---- K3: G-GEMM (32x32x16 MFMA), small-LDS high-occupancy version ----------
// grid (rc=32, dq=32, js=4) = 4096 blocks, 256 thr (4 waves), 36 KB LDS
// -> 4 blocks/CU = 16 waves/CU (was 8). Wave w: rows [w*64,+64) (2 rt),
// full K, 4 d. xv loaded DIRECTLY from global (f32, L2-served, 32x reuse)
// -- no x staging phase, one barrier before compute. launch_bounds(256,4)
// pins <=128 VGPR.
__global__ __launch_bounds__(256, 4) void k3_gemm(
    const float* __restrict__ x, const short* __restrict__ embh3,
    const short* __restrict__ qrh2, float* __restrict__ part)
{
    __shared__ __align__(16) short elds[4 * 4096];   // 32 KB
    __shared__ float sof[256 * 4];                   // 4 KB
    int t = threadIdx.x, w = t >> 6, l = t & 63;
    int l31 = l & 31, hi = l >> 5;
    int rc = blockIdx.x, dq = blockIdx.y, js = blockIdx.z;

    // issue emb staging first (4 d x 32 j x 128 k = 32 KB)
#pragma unroll
    for (int i = 0; i < 8; ++i) {
        int c = i * 256 + t;
        int d = c >> 9, off = c & 511;
        gload_lds16(embh3 + (size_t)((dq * 4 + d) * 4 + js) * 4096 + (size_t)off * 8,
                    elds + (size_t)(i * 256 + w * 64) * 8);
    }

    // B fragments (overlap staging latency)
    bf16x8 Bf[2][8];
#pragma unroll
    for (int rt = 0; rt < 2; ++rt) {
        int R32 = rc * 8 + w * 2 + rt;
#pragma unroll
        for (int s = 0; s < 8; ++s)
            Bf[rt][s] = *(const bf16x8*)(qrh2 + (((size_t)R32 * 8 + s) * 64 + l) * 8);
    }

    // xv direct from global: xv[rt][4*g4+q] = x[row, js*32 + 8*g4 + 4*hi + q]
    float xv[2][16];
#pragma unroll
    for (int rt = 0; rt < 2; ++rt) {
        int row = rc * 256 + w * 64 + rt * 32 + l31;
#pragma unroll
        for (int g4 = 0; g4 < 4; ++g4) {
            float4 v = *(const float4*)(x + (size_t)row * 128 + js * 32 + g4 * 8 + 4 * hi);
            xv[rt][g4 * 4 + 0] = v.x;
            xv[rt][g4 * 4 + 1] = v.y;
            xv[rt][g4 * 4 + 2] = v.z;
            xv[rt][g4 * 4 + 3] = v.w;
        }
    }

    __syncthreads();   // drains vmcnt: staging + Bf + xv all complete

    float sout[2][4];
#pragma unroll
    for (int d = 0; d < 4; ++d) {
        bf16x8 A[8];
#pragma unroll
        for (int s = 0; s < 8; ++s)
            A[s] = *(const bf16x8*)(elds + d * 4096 + (s * 64 + l) * 8);
#pragma unroll
        for (int rt = 0; rt < 2; ++rt) {
            f32x16 acc;
#pragma unroll
            for (int q = 0; q < 16; ++q) acc[q] = 0.f;
#pragma unroll
            for (int s = 0; s < 8; ++s)
                acc = __builtin_amdgcn_mfma_f32_32x32x16_bf16(A[s], Bf[rt][s],
                                                              acc, 0, 0, 0);
            float s0 = 0.f, s1 = 0.f, s2 = 0.f, s3 = 0.f;
#pragma unroll
            for (int q = 0; q < 4; ++q) {
                s0 = fmaf(xv[rt][q * 4 + 0], acc[q * 4 + 0], s0);
                s1 = fmaf(xv[rt][q * 4 + 1], acc[q * 4 + 1], s1);
                s2 = fmaf(xv[rt][q * 4 + 2], acc[q * 4 + 2], s2);
                s3 = fmaf(xv[rt][q * 4 + 3], acc[q * 4 + 3], s3);
            }
            float sm = (s0 + s1) + (s2 + s3);
            sm += __shfl_xor(sm, 32);
            sout[rt][d] = sm;
        }
    }

    __syncthreads();
    if (hi == 0) {
#pragma unroll
        for (int rt = 0; rt < 2; ++rt)
#pragma unroll
            for (int d = 0; d < 4; ++d)
                sof[(w * 64 + rt * 32 + l31) * 4 + d] = sout[rt][d];
    }
    __syncthreads();

    // writeout: thread t -> row t, 4 d-cols (16B)
    {
        float4 v = *(const float4*)&sof[t * 4];
        *(float4*)(part + (size_t)js * (NROWS * DD)
                   + (size_t)(rc * 256 + t) * 128 + dq * 4) = v;
    }
}

// ---- K4: sum 4 f32 partials + x, LayerNorm ---------------------------------
__global__ __launch_bounds__(256) void k4_ln(
    const float* __restrict__ x, const float* __restrict__ part,
    const float* __restrict__ gamma, const float* __restrict__ beta,
    float* __restrict__ out)
{
    int wave = threadIdx.x >> 6, lane = threadIdx.x & 63;
    int row = blockIdx.x * 4 + wave;
    size_t base = (size_t)row * DD;
    float r0 = x[base + lane], r1 = x[base + lane + 64];
#pragma unroll
    for (int p = 0; p < 4; ++p) {
        r0 += part[(size_t)p * NROWS * DD + base + lane];
        r1 += part[(size_t)p * NROWS * DD + base + lane + 64];
    }
    float s = r0 + r1, s2 = r0 * r0 + r1 * r1;
#pragma unroll
    for (int off = 32; off > 0; off >>= 1) {
        s += __shfl_xor(s, off);
        s2 += __shfl_xor(s2, off);
    }
    float mu = s * (1.0f / DD);
    float var = s2 * (1.0f / DD) - mu * mu;
    var = fmaxf(var, 0.0f);
    float rs = rsqrtf(var + LN_EPSF);
    out[base + lane] = (r0 - mu) * rs * gamma[lane] + beta[lane];
    out[base + lane + 64] = (r1 - mu) * rs * gamma[lane + 64] + beta[lane + 64];
}

extern "C" void kernel_launch(void* const* d_in, const int* in_sizes, int n_in,
                              void* d_out, int out_size, void* d_ws, size_t ws_size,
                              hipStream_t stream) {
    const float* x     = (const float*)d_in[0];
    const float* Wq    = (const float*)d_in[1];
    const float* bq    = (const float*)d_in[2];
    const float* Wm    = (const float*)d_in[3];
    const float* bm    = (const float*)d_in[4];
    const float* Ww    = (const float*)d_in[5];
    const float* bw    = (const float*)d_in[6];
    const float* Wc    = (const float*)d_in[7];
    const float* bc    = (const float*)d_in[8];
    const float* emb   = (const float*)d_in[9];
    const float* gamma = (const float*)d_in[10];
    const float* beta  = (const float*)d_in[11];
    float* out = (float*)d_out;
    float* ws  = (float*)d_ws;

    short* embh3 = (short*)ws;                  // 4 MB
    short* qrh2  = (short*)(ws + 1048576);      // 2 MB
    float* scal  = ws + 1572864;
    float* part  = ws + 1605632;                // 16 MB (4 f32 planes)
    float* tr    = ws + 1605632;                // transients alias part
    short* xh2   = (short*)tr;
    short* xl2   = (short*)(tr + 524288);
    float* mq    = tr + 1048576;
    float* mo    = tr + 2097152;
    short* Wfrag = (short*)(tr + 3145728);

    hipLaunchKernelGGL(k0a_emb,   dim3(128, 4), dim3(256), 0, stream, emb, embh3);
    hipLaunchKernelGGL(k0w_split, dim3(256),    dim3(256), 0, stream, Wq, Wm, Wfrag);
    hipLaunchKernelGGL(k0c_xsplit,dim3(256),    dim3(256), 0, stream,
                       x, Ww, bw, Wc, bc, xh2, xl2, scal);
    hipLaunchKernelGGL(k1_mfma,   dim3(256),    dim3(256), 0, stream,
                       xh2, xl2, Wfrag, bq, bm, mq, mo, scal);
    hipLaunchKernelGGL(k2_qr,     dim3(8192),   dim3(256), 0, stream,
                       x, mq, mo, scal, qrh2);
    hipLaunchKernelGGL(k3_gemm,   dim3(32, 32, 4), dim3(256), 0, stream,
                       x, embh3, qrh2, part);
    hipLaunchKernelGGL(k4_ln,     dim3(2048),   dim3(256), 0, stream,
                       x, part, gamma, beta, out);
}

// Round 10
// 98.454 us; speedup vs baseline: 2.2394x; 2.2394x over previous
//
#include <hip/hip_runtime.h>
#include <hip/hip_bf16.h>
#include <math.h>

#define DD 128
#define SS 1024
#define NROWS 8192
#define EPSF 1e-7f
#define LN_EPSF 1e-3f
#define TCUT 30.0f

typedef __attribute__((ext_vector_type(8))) short bf16x8;
typedef __attribute__((ext_vector_type(4))) float f32x4;
typedef __attribute__((ext_vector_type(16))) float f32x16;

__device__ __forceinline__ void gload_lds16(const void* g, void* l) {
    __builtin_amdgcn_global_load_lds(
        (const __attribute__((address_space(1))) unsigned int*)g,
        (__attribute__((address_space(3))) unsigned int*)l, 16, 0, 0);
}
__device__ __forceinline__ short f2bf(float v) {
    union { __hip_bfloat16 h; short s; } u;
    u.h = __float2bfloat16(v);
    return u.s;
}
__device__ __forceinline__ float bf2f(short s) {
    union { __hip_bfloat16 h; short s; } u; u.s = s;
    return __bfloat162float(u.h);
}
__device__ __forceinline__ unsigned int pack_bf16(float lo, float hi) {
    unsigned int r;
    asm("v_cvt_pk_bf16_f32 %0, %1, %2" : "=v"(r) : "v"(lo), "v"(hi));
    return r;
}
__device__ __forceinline__ float u2f(unsigned int u) {
    union { unsigned int u; float f; } c; c.u = u; return c.f;
}

// ---- K0a: emb -> bf16 fragment-linear: embh3[(d*4+js)*4096 + (ks*64+l)*8+e]
//      = emb[d][js*32 + (l&31)][ks*16 + (l>>5)*8 + e]
__global__ __launch_bounds__(256) void k0a_emb(const float* __restrict__ emb,
                                               short* __restrict__ embh3) {
    __shared__ float lt[32][128];
    int d = blockIdx.x, js = blockIdx.y, t = threadIdx.x;
    {
        int jl = t >> 3, k0 = (t & 7) * 16;
        const float4* src = (const float4*)(emb + (size_t)d * 16384
                                            + (size_t)(js * 32 + jl) * 128 + k0);
#pragma unroll
        for (int q = 0; q < 4; ++q) *(float4*)&lt[jl][k0 + q * 4] = src[q];
    }
    __syncthreads();
    int ks = t >> 5, l0 = (t & 31) * 2;
    union { bf16x8 v[2]; short s[16]; } ob;
#pragma unroll
    for (int li = 0; li < 2; ++li) {
        int l = l0 + li;
        const float* p = &lt[l & 31][ks * 16 + (l >> 5) * 8];
#pragma unroll
        for (int e = 0; e < 8; ++e) ob.s[li * 8 + e] = f2bf(p[e]);
    }
    short* dst = embh3 + (size_t)(d * 4 + js) * 4096 + (size_t)t * 16;
    *(bf16x8*)dst = ob.v[0];
    *(bf16x8*)(dst + 8) = ob.v[1];
}

// ---- K0w: split Wq|Wm into bf16 hi/lo fragment-linear for k1 --------------
__global__ __launch_bounds__(256) void k0w_split(const float* __restrict__ Wq,
        const float* __restrict__ Wm, short* __restrict__ Wfrag) {
    int T = blockIdx.x * 256 + threadIdx.x;       // 65536 total
    int e = T & 7, l = (T >> 3) & 63, ks = (T >> 9) & 3, nt = (T >> 11) & 7,
        mat = (T >> 14) & 1;
    int k = ks * 32 + ((l >> 4) & 3) * 8 + e;
    int c = nt * 16 + (l & 15);
    float v = (mat ? Wm : Wq)[k * 128 + c];
    short h = f2bf(v);
    float lo = v - bf2f(h);
    Wfrag[((((size_t)(mat * 2 + 0) * 8 + nt) * 4 + ks) * 64 + l) * 8 + e] = h;
    Wfrag[((((size_t)(mat * 2 + 1) * 8 + nt) * 4 + ks) * 64 + l) * 8 + e] = f2bf(lo);
}

// ---- K0c: x -> xh2/xl2 (frag-linear for k1) + w,c scalars ------------------
__global__ __launch_bounds__(256) void k0c_xsplit(const float* __restrict__ x,
        const float* __restrict__ Ww, const float* __restrict__ bw,
        const float* __restrict__ Wc, const float* __restrict__ bc,
        short* __restrict__ xh2, short* __restrict__ xl2,
        float* __restrict__ scal) {
    __shared__ float xs[32][129];
    int rb = blockIdx.x, t = threadIdx.x;
    {
        int r = t >> 3, d0 = (t & 7) * 16;
        const float4* src = (const float4*)(x + (size_t)(rb * 32 + r) * 128 + d0);
#pragma unroll
        for (int q = 0; q < 4; ++q) *(float4*)&xs[r][d0 + q * 4] = src[q];
    }
    __syncthreads();
    int ks = (t >> 5) & 3, rf = t >> 7, l0 = (t & 31) * 2;
    union { bf16x8 v[2]; short s[16]; } hb, lb;
#pragma unroll
    for (int li = 0; li < 2; ++li) {
        int l = l0 + li;
        const float* p = &xs[rf * 16 + (l & 15)][ks * 32 + ((l >> 4) & 3) * 8];
#pragma unroll
        for (int e = 0; e < 8; ++e) {
            float v = p[e];
            short h = f2bf(v);
            hb.s[li * 8 + e] = h;
            lb.s[li * 8 + e] = f2bf(v - bf2f(h));
        }
    }
    {
        short* d1 = xh2 + (size_t)rb * 4096 + (size_t)t * 16;
        short* d2 = xl2 + (size_t)rb * 4096 + (size_t)t * 16;
        *(bf16x8*)d1 = hb.v[0]; *(bf16x8*)(d1 + 8) = hb.v[1];
        *(bf16x8*)d2 = lb.v[0]; *(bf16x8*)(d2 + 8) = lb.v[1];
    }
    // w, c scalars
    int rr = t >> 3, seg = t & 7;
    float pw = 0.f, pc = 0.f;
#pragma unroll
    for (int dq = 0; dq < 16; ++dq) {
        float xv = xs[rr][seg * 16 + dq];
        pw = fmaf(xv, Ww[seg * 16 + dq], pw);
        pc = fmaf(xv, Wc[seg * 16 + dq], pc);
    }
    pw += __shfl_xor(pw, 1); pw += __shfl_xor(pw, 2); pw += __shfl_xor(pw, 4);
    pc += __shfl_xor(pc, 1); pc += __shfl_xor(pc, 2); pc += __shfl_xor(pc, 4);
    if (seg == 0) {
        scal[(size_t)(rb * 32 + rr) * 4 + 0] = fmaxf(pw + bw[0], 0.f);
        scal[(size_t)(rb * 32 + rr) * 4 + 1] = fmaxf(pc + bc[0], 0.f);
    }
}

// ---- K1: q'/m via split-bf16 MFMA (3 products each), fused epilogue --------
__global__ __launch_bounds__(256) void k1_mfma(
    const short* __restrict__ xh2, const short* __restrict__ xl2,
    const short* __restrict__ Wfrag,
    const float* __restrict__ bq, const float* __restrict__ bm,
    float* __restrict__ mq, float* __restrict__ mo, float* __restrict__ scal)
{
    __shared__ __align__(16) short wl[65536];   // 128 KB
    __shared__ float red[32][4][2];
    int t = threadIdx.x, w = t >> 6, l = t & 63;
    int l15 = l & 15, g = l >> 4;
    int row0 = blockIdx.x * 32;
#pragma unroll
    for (int it = 0; it < 32; ++it)
        gload_lds16(Wfrag + (size_t)(it * 256 + t) * 8, wl + (size_t)(it * 256 + w * 64) * 8);
    const short* xb  = xh2 + (size_t)blockIdx.x * 4096;
    const short* xlb = xl2 + (size_t)blockIdx.x * 4096;
    bf16x8 Ah[2][4], Al[2][4];
#pragma unroll
    for (int rf = 0; rf < 2; ++rf)
#pragma unroll
        for (int ks = 0; ks < 4; ++ks) {
            size_t o = ((size_t)(rf * 4 + ks) * 64 + l) * 8;
            Ah[rf][ks] = *(const bf16x8*)(xb + o);
            Al[rf][ks] = *(const bf16x8*)(xlb + o);
        }
    __syncthreads();
    f32x4 accq[2][2] = {}, accm[2][2] = {};
#pragma unroll
    for (int ntp = 0; ntp < 2; ++ntp) {
        int nt = w * 2 + ntp;
#pragma unroll
        for (int ks = 0; ks < 4; ++ks) {
            bf16x8 bhq = *(const bf16x8*)(wl + ((size_t)(0  + nt) * 4 + ks) * 512 + l * 8);
            bf16x8 blq = *(const bf16x8*)(wl + ((size_t)(8  + nt) * 4 + ks) * 512 + l * 8);
            bf16x8 bhm = *(const bf16x8*)(wl + ((size_t)(16 + nt) * 4 + ks) * 512 + l * 8);
            bf16x8 blm = *(const bf16x8*)(wl + ((size_t)(24 + nt) * 4 + ks) * 512 + l * 8);
#pragma unroll
            for (int rf = 0; rf < 2; ++rf) {
                accq[rf][ntp] = __builtin_amdgcn_mfma_f32_16x16x32_bf16(Ah[rf][ks], bhq, accq[rf][ntp], 0, 0, 0);
                accq[rf][ntp] = __builtin_amdgcn_mfma_f32_16x16x32_bf16(Ah[rf][ks], blq, accq[rf][ntp], 0, 0, 0);
                accq[rf][ntp] = __builtin_amdgcn_mfma_f32_16x16x32_bf16(Al[rf][ks], bhq, accq[rf][ntp], 0, 0, 0);
                accm[rf][ntp] = __builtin_amdgcn_mfma_f32_16x16x32_bf16(Ah[rf][ks], bhm, accm[rf][ntp], 0, 0, 0);
                accm[rf][ntp] = __builtin_amdgcn_mfma_f32_16x16x32_bf16(Ah[rf][ks], blm, accm[rf][ntp], 0, 0, 0);
                accm[rf][ntp] = __builtin_amdgcn_mfma_f32_16x16x32_bf16(Al[rf][ks], bhm, accm[rf][ntp], 0, 0, 0);
            }
        }
    }
    float sq1[2][4] = {{0,0,0,0},{0,0,0,0}};
    float sq2[2][4] = {{0,0,0,0},{0,0,0,0}};
#pragma unroll
    for (int ntp = 0; ntp < 2; ++ntp) {
        int c = (w * 2 + ntp) * 16 + l15;
        float bqv = bq[c] + EPSF, bmv = bm[c];
#pragma unroll
        for (int rf = 0; rf < 2; ++rf)
#pragma unroll
            for (int reg = 0; reg < 4; ++reg) {
                int rloc = rf * 16 + g * 4 + reg;
                float qp = accq[rf][ntp][reg] + bqv;
                float mv = 1.0f / (1.0f + expf(-(accm[rf][ntp][reg] + bmv)));
                size_t o = (size_t)(row0 + rloc) * 128 + c;
                mq[o] = mv * qp;
                mo[o] = mv;
                sq1[rf][reg] += qp;
                sq2[rf][reg] += qp * qp;
            }
    }
#pragma unroll
    for (int rf = 0; rf < 2; ++rf)
#pragma unroll
        for (int reg = 0; reg < 4; ++reg) {
            float a = sq1[rf][reg], b = sq2[rf][reg];
            a += __shfl_xor(a, 1); a += __shfl_xor(a, 2);
            a += __shfl_xor(a, 4); a += __shfl_xor(a, 8);
            b += __shfl_xor(b, 1); b += __shfl_xor(b, 2);
            b += __shfl_xor(b, 4); b += __shfl_xor(b, 8);
            if (l15 == 0) {
                red[rf * 16 + g * 4 + reg][w][0] = a;
                red[rf * 16 + g * 4 + reg][w][1] = b;
            }
        }
    __syncthreads();
    if (t < 32) {
        float a = red[t][0][0] + red[t][1][0] + red[t][2][0] + red[t][3][0];
        float b = red[t][0][1] + red[t][1][1] + red[t][2][1] + red[t][3][1];
        scal[(size_t)(row0 + t) * 4 + 2] = a;
        scal[(size_t)(row0 + t) * 4 + 3] = sqrtf(b);
    }
}

// ---- K2: windowed pair loop -> qrh2. One row/block; 4 waves x 4 groups of
//      16 lanes = 16 dists per iteration; lane owns 8 d-elements.
__global__ __launch_bounds__(256) void k2_qr(
    const float* __restrict__ x,
    const float* __restrict__ mq, const float* __restrict__ mo,
    const float* __restrict__ scal, short* __restrict__ qrh2)
{
    int row = blockIdx.x;
    int i = row & (SS - 1);
    const float* xb = x + (size_t)(row - i) * DD;
    int t = threadIdx.x, w = t >> 6, l = t & 63;
    int sub = l >> 4, q = l & 15;
    int qo = q * 8;

    float mqv[8], mov[8];
    {
        const float* mp = mq + (size_t)row * DD + qo;
        float4 a = *(const float4*)mp, b = *(const float4*)(mp + 4);
        mqv[0] = a.x; mqv[1] = a.y; mqv[2] = a.z; mqv[3] = a.w;
        mqv[4] = b.x; mqv[5] = b.y; mqv[6] = b.z; mqv[7] = b.w;
        const float* op = mo + (size_t)row * DD + qo;
        float4 c = *(const float4*)op, d = *(const float4*)(op + 4);
        mov[0] = c.x; mov[1] = c.y; mov[2] = c.z; mov[3] = c.w;
        mov[4] = d.x; mov[5] = d.y; mov[6] = d.z; mov[7] = d.w;
    }
    float wv = scal[row * 4 + 0], cv = scal[row * 4 + 1];
    float sumqp = scal[row * 4 + 2], nb = scal[row * 4 + 3];
    float wi = wv + EPSF;
    float dmaxf = cv + TCUT * wi;
    int dmax = (dmaxf >= (float)i) ? i : (int)dmaxf;

    float acc[8] = {0.f, 0.f, 0.f, 0.f, 0.f, 0.f, 0.f, 0.f};
    int nit = (dmax + 15) >> 4;
    int dbase = 1 + w * 4 + sub;
    for (int it = 0; it < nit; ++it) {
        int dist = dbase + it * 16;
        float xv[8];
        if (dist <= dmax) {
            const float* xp = xb + (size_t)(i - dist) * DD + qo;
            float4 a = *(const float4*)xp, b = *(const float4*)(xp + 4);
            xv[0] = a.x; xv[1] = a.y; xv[2] = a.z; xv[3] = a.w;
            xv[4] = b.x; xv[5] = b.y; xv[6] = b.z; xv[7] = b.w;
        } else {
#pragma unroll
            for (int e = 0; e < 8; ++e) xv[e] = 0.f;
        }
        float t1 = 0.f, s1 = 0.f, s2 = 0.f;
#pragma unroll
        for (int e = 0; e < 8; ++e) {
            float xm = xv[e] * mov[e];
            t1 = fmaf(xv[e], mqv[e], t1);
            s1 += xm;
            s2 = fmaf(xm, xm, s2);
        }
#pragma unroll
        for (int off = 1; off < 16; off <<= 1) {
            t1 += __shfl_xor(t1, off);
            s1 += __shfl_xor(s1, off);
            s2 += __shfl_xor(s2, off);
        }
        float tt = ((float)dist - cv) / wi;
        float pe = 1.0f / coshf(tt);
        float dotv = fmaf(pe, t1, EPSF * sumqp);
        float na = sqrtf(fmaf(pe * pe, s2,
                         fmaf(2.0f * EPSF * pe, s1, (float)DD * EPSF * EPSF)));
        float cosv = fminf(1.0f, fmaxf(-1.0f, dotv / (na * nb)));
        float ang = acosf(cosv);
        float wgt = pe * ang;
#pragma unroll
        for (int e = 0; e < 8; ++e) acc[e] = fmaf(wgt, xv[e], acc[e]);
    }
#pragma unroll
    for (int e = 0; e < 8; ++e) {
        acc[e] += __shfl_xor(acc[e], 16);
        acc[e] += __shfl_xor(acc[e], 32);
    }
    __shared__ float sq[4][DD];
    if (l < 16) {
#pragma unroll
        for (int e = 0; e < 8; ++e) sq[w][qo + e] = acc[e];
    }
    __syncthreads();
    if (t < DD) {
        float v = sq[0][t] + sq[1][t] + sq[2][t] + sq[3][t];
        int rbq = row >> 7, rr = row & 127, rt2 = rr >> 5, lp = rr & 31;
        int k = t;
        qrh2[(((size_t)(rbq * 4 + rt2) * 8 + (k >> 4)) * 64
              + (lp + 32 * ((k >> 3) & 1))) * 8 + (k & 7)] = f2bf(v);
    }
}

// ---- K3: G-GEMM (32x32x16 MFMA), rt=4 / kp-split, dbuf emb staging ---------
// grid (rc=32, dqb=4, js=4) = 512 blocks, 256 thr (4 waves = rh2 x kp2),
// 64 KB LDS -> 2 blocks/CU (2 waves/SIMD). Wave: 4 row-tiles (128 rows,
// 4 indep MFMA chains) x K-half (Bf 64 VGPR) x all 4 d of sub-tile.
// 8 sub-tiles of 4 d, ping-pong staged: stage(st+1) issued before compute(st);
// barrier drain lands after compute. xv kept as packed-bf16 pairs (32 VGPR).
// kp partials -> 8 bf16 planes (summed in k4). ~196 VGPR live -> no spill.
__global__ __launch_bounds__(256, 2) void k3_gemm(
    const float* __restrict__ x, const short* __restrict__ embh3,
    const short* __restrict__ qrh2, short* __restrict__ partb)
{
    __shared__ __align__(16) short elds[2][16384];   // 2 x 32 KB ping-pong
    short* xtwh = &elds[0][0];                       // [256][34] bf16, aliases buf0

    int t = threadIdx.x, w = t >> 6, l = t & 63;
    int l31 = l & 31, hi = l >> 5;
    int kp = w & 1, rh = w >> 1;
    int rc = blockIdx.x, dqb = blockIdx.y, js = blockIdx.z;

    // phase 1: stage x tile (256 r x 32 j) as bf16 into xtwh (stride 34)
#pragma unroll
    for (int i = 0; i < 8; ++i) {
        int idx = i * 256 + t;
        int r = idx >> 3, j4 = (idx & 7) * 4;
        float4 v = *(const float4*)(x + (size_t)(rc * 256 + r) * 128 + js * 32 + j4);
        *(unsigned int*)(xtwh + r * 34 + j4)     = pack_bf16(v.x, v.y);
        *(unsigned int*)(xtwh + r * 34 + j4 + 2) = pack_bf16(v.z, v.w);
    }

    // issue sub-tile 0 staging into buf1 (overlaps phase 1 drain)
    {
        int dgb = dqb * 32;
#pragma unroll
        for (int i = 0; i < 8; ++i) {
            int c = i * 256 + t;
            int d = c >> 9, off = c & 511;
            gload_lds16(embh3 + (size_t)((dgb + d) * 4 + js) * 4096 + (size_t)off * 8,
                        &elds[1][0] + (size_t)(i * 256 + w * 64) * 8);
        }
    }

    // B fragments: own kp K-half, 4 row-tiles (64 VGPR)
    bf16x8 Bf[4][4];
#pragma unroll
    for (int rt = 0; rt < 4; ++rt) {
        int R32 = rc * 8 + rh * 4 + rt;
#pragma unroll
        for (int s = 0; s < 4; ++s)
            Bf[rt][s] = *(const bf16x8*)(qrh2
                + (((size_t)R32 * 8 + kp * 4 + s) * 64 + l) * 8);
    }

    __syncthreads();   // drains xtwh writes + st0 staging + Bf

    // xv extract, kept packed (stride 17 u32-words -> conflict-free)
    unsigned int xvp[4][8];
#pragma unroll
    for (int rt = 0; rt < 4; ++rt) {
        int row_l = rh * 128 + rt * 32 + l31;
#pragma unroll
        for (int p = 0; p < 8; ++p) {
            int jA = ((2 * p) & 3) + 8 * (p >> 1) + 4 * hi;
            xvp[rt][p] = *(const unsigned int*)(xtwh + row_l * 34 + jA);
        }
    }
    __syncthreads();   // all waves done with xtwh (buf0 now free)

    size_t pbase = (size_t)(js * 2 + kp) * ((size_t)NROWS * DD);
    float sprev[4];

#pragma unroll 1
    for (int st = 0; st < 8; ++st) {
        // stage next sub-tile into the buffer not being read
        if (st < 7) {
            int dgb = dqb * 32 + (st + 1) * 4;
            short* dstb = &elds[st & 1][0];
#pragma unroll
            for (int i = 0; i < 8; ++i) {
                int c = i * 256 + t;
                int d = c >> 9, off = c & 511;
                gload_lds16(embh3 + (size_t)((dgb + d) * 4 + js) * 4096 + (size_t)off * 8,
                            dstb + (size_t)(i * 256 + w * 64) * 8);
            }
        }
        const short* eb = &elds[(st + 1) & 1][0];

#pragma unroll
        for (int dloc = 0; dloc < 4; ++dloc) {
            bf16x8 A[4];
#pragma unroll
            for (int s = 0; s < 4; ++s)
                A[s] = *(const bf16x8*)(eb + dloc * 4096 + ((kp * 4 + s) * 64 + l) * 8);
            f32x16 acc[4];
#pragma unroll
            for (int rt = 0; rt < 4; ++rt)
#pragma unroll
                for (int q = 0; q < 16; ++q) acc[rt][q] = 0.f;
#pragma unroll
            for (int s = 0; s < 4; ++s)
#pragma unroll
                for (int rt = 0; rt < 4; ++rt)
                    acc[rt] = __builtin_amdgcn_mfma_f32_32x32x16_bf16(
                        A[s], Bf[rt][s], acc[rt], 0, 0, 0);
#pragma unroll
            for (int rt = 0; rt < 4; ++rt) {
                float s0 = 0.f, s1 = 0.f, s2 = 0.f, s3 = 0.f;
#pragma unroll
                for (int p = 0; p < 8; p += 2) {
                    unsigned int u0 = xvp[rt][p], u1 = xvp[rt][p + 1];
                    s0 = fmaf(u2f(u0 << 16),          acc[rt][2 * p],     s0);
                    s1 = fmaf(u2f(u0 & 0xFFFF0000u),  acc[rt][2 * p + 1], s1);
                    s2 = fmaf(u2f(u1 << 16),          acc[rt][2 * p + 2], s2);
                    s3 = fmaf(u2f(u1 & 0xFFFF0000u),  acc[rt][2 * p + 3], s3);
                }
                float sm = (s0 + s1) + (s2 + s3);
                sm += __shfl_xor(sm, 32);
                if ((dloc & 1) == 0) {
                    sprev[rt] = sm;
                } else if (hi == 0) {
                    int row_g = rc * 256 + rh * 128 + rt * 32 + l31;
                    int dg = dqb * 32 + st * 4 + (dloc - 1);
                    *(unsigned int*)(partb + pbase + (size_t)row_g * 128 + dg)
                        = pack_bf16(sprev[rt], sm);
                }
            }
        }
        __syncthreads();   // drains next-tile staging; all waves done reading eb
    }
}

// ---- K4: sum 8 bf16 partials + x, LayerNorm --------------------------------
__global__ __launch_bounds__(256) void k4_ln(
    const float* __restrict__ x, const short* __restrict__ partb,
    const float* __restrict__ gamma, const float* __restrict__ beta,
    float* __restrict__ out)
{
    int wave = threadIdx.x >> 6, lane = threadIdx.x & 63;
    int row = blockIdx.x * 4 + wave;
    size_t base = (size_t)row * DD;
    float r0 = x[base + lane], r1 = x[base + lane + 64];
#pragma unroll
    for (int p = 0; p < 8; ++p) {
        r0 += bf2f(partb[(size_t)p * 1048576 + base + lane]);
        r1 += bf2f(partb[(size_t)p * 1048576 + base + lane + 64]);
    }
    float s = r0 + r1, s2 = r0 * r0 + r1 * r1;
#pragma unroll
    for (int off = 32; off > 0; off >>= 1) {
        s += __shfl_xor(s, off);
        s2 += __shfl_xor(s2, off);
    }
    float mu = s * (1.0f / DD);
    float var = s2 * (1.0f / DD) - mu * mu;
    var = fmaxf(var, 0.0f);
    float rs = rsqrtf(var + LN_EPSF);
    out[base + lane] = (r0 - mu) * rs * gamma[lane] + beta[lane];
    out[base + lane + 64] = (r1 - mu) * rs * gamma[lane + 64] + beta[lane + 64];
}

extern "C" void kernel_launch(void* const* d_in, const int* in_sizes, int n_in,
                              void* d_out, int out_size, void* d_ws, size_t ws_size,
                              hipStream_t stream) {
    const float* x     = (const float*)d_in[0];
    const float* Wq    = (const float*)d_in[1];
    const float* bq    = (const float*)d_in[2];
    const float* Wm    = (const float*)d_in[3];
    const float* bm    = (const float*)d_in[4];
    const float* Ww    = (const float*)d_in[5];
    const float* bw    = (const float*)d_in[6];
    const float* Wc    = (const float*)d_in[7];
    const float* bc    = (const float*)d_in[8];
    const float* emb   = (const float*)d_in[9];
    const float* gamma = (const float*)d_in[10];
    const float* beta  = (const float*)d_in[11];
    float* out = (float*)d_out;
    float* ws  = (float*)d_ws;

    short* embh3 = (short*)ws;                  // 4 MB
    short* qrh2  = (short*)(ws + 1048576);      // 2 MB
    float* scal  = ws + 1572864;
    short* partb = (short*)(ws + 1605632);      // 16 MB (8 bf16 planes)
    float* tr    = ws + 1605632;                // transients alias partb
    short* xh2   = (short*)tr;
    short* xl2   = (short*)(tr + 524288);
    float* mq    = tr + 1048576;
    float* mo    = tr + 2097152;
    short* Wfrag = (short*)(tr + 3145728);

    hipLaunchKernelGGL(k0a_emb,   dim3(128, 4), dim3(256), 0, stream, emb, embh3);
    hipLaunchKernelGGL(k0w_split, dim3(256),    dim3(256), 0, stream, Wq, Wm, Wfrag);
    hipLaunchKernelGGL(k0c_xsplit,dim3(256),    dim3(256), 0, stream,
                       x, Ww, bw, Wc, bc, xh2, xl2, scal);
    hipLaunchKernelGGL(k1_mfma,   dim3(256),    dim3(256), 0, stream,
                       xh2, xl2, Wfrag, bq, bm, mq, mo, scal);
    hipLaunchKernelGGL(k2_qr,     dim3(8192),   dim3(256), 0, stream,
                       x, mq, mo, scal, qrh2);
    hipLaunchKernelGGL(k3_gemm,   dim3(32, 4, 4), dim3(256), 0, stream,
                       x, embh3, qrh2, partb);
    hipLaunchKernelGGL(k4_ln,     dim3(2048),   dim3(256), 0, stream,
                       x, partb, gamma, beta, out);
}

// Round 11
// 89.520 us; speedup vs baseline: 2.4629x; 1.0998x over previous
//
#include <hip/hip_runtime.h>
#include <hip/hip_bf16.h>
#include <math.h>

#define DD 128
#define SS 1024
#define NROWS 8192
#define EPSF 1e-7f
#define LN_EPSF 1e-3f
#define TCUT 30.0f

typedef __attribute__((ext_vector_type(8))) short bf16x8;
typedef __attribute__((ext_vector_type(4))) float f32x4;
typedef __attribute__((ext_vector_type(16))) float f32x16;

__device__ __forceinline__ void gload_lds16(const void* g, void* l) {
    __builtin_amdgcn_global_load_lds(
        (const __attribute__((address_space(1))) unsigned int*)g,
        (__attribute__((address_space(3))) unsigned int*)l, 16, 0, 0);
}
__device__ __forceinline__ short f2bf(float v) {
    union { __hip_bfloat16 h; short s; } u;
    u.h = __float2bfloat16(v);
    return u.s;
}
__device__ __forceinline__ float bf2f(short s) {
    union { __hip_bfloat16 h; short s; } u; u.s = s;
    return __bfloat162float(u.h);
}
__device__ __forceinline__ unsigned int pack_bf16(float lo, float hi) {
    unsigned int r;
    asm("v_cvt_pk_bf16_f32 %0, %1, %2" : "=v"(r) : "v"(lo), "v"(hi));
    return r;
}
__device__ __forceinline__ float u2f(unsigned int u) {
    union { unsigned int u; float f; } c; c.u = u; return c.f;
}

// ---- K0a: emb -> bf16 B-fragment layout for k3:
//   embB[j*16384 + dt*4096 + s*512 + l*8 + e]
//     = emb[dt*32 + (l&31)][j][s*16 + (l>>5)*8 + e]
// (B-operand of 32x32x16: col = l&31 (d), k = (l>>5)*8+e)
__global__ __launch_bounds__(256) void k0a_emb(const float* __restrict__ emb,
                                               short* __restrict__ embB) {
    __shared__ float lt[128][132];
    int j = blockIdx.x, t = threadIdx.x;
    {
        int d = t >> 1, kh = (t & 1) * 64;
        const float* src = emb + (size_t)d * 16384 + (size_t)j * 128 + kh;
#pragma unroll
        for (int q = 0; q < 16; ++q)
            *(float4*)&lt[d][kh + q * 4] = *(const float4*)(src + q * 4);
    }
    __syncthreads();
#pragma unroll
    for (int i = 0; i < 8; ++i) {
        int idx = i * 256 + t;
        int l = idx & 63, s = (idx >> 6) & 7, dt = (idx >> 9) & 3;
        const float* p = &lt[dt * 32 + (l & 31)][s * 16 + (l >> 5) * 8];
        union { bf16x8 v; short sa[8]; } ob;
#pragma unroll
        for (int e = 0; e < 8; ++e) ob.sa[e] = f2bf(p[e]);
        *(bf16x8*)(embB + (size_t)j * 16384 + dt * 4096 + s * 512 + (size_t)l * 8) = ob.v;
    }
}

// ---- K0w: split Wq|Wm into bf16 hi/lo fragment-linear for k1 --------------
__global__ __launch_bounds__(256) void k0w_split(const float* __restrict__ Wq,
        const float* __restrict__ Wm, short* __restrict__ Wfrag) {
    int T = blockIdx.x * 256 + threadIdx.x;       // 65536 total
    int e = T & 7, l = (T >> 3) & 63, ks = (T >> 9) & 3, nt = (T >> 11) & 7,
        mat = (T >> 14) & 1;
    int k = ks * 32 + ((l >> 4) & 3) * 8 + e;
    int c = nt * 16 + (l & 15);
    float v = (mat ? Wm : Wq)[k * 128 + c];
    short h = f2bf(v);
    float lo = v - bf2f(h);
    Wfrag[((((size_t)(mat * 2 + 0) * 8 + nt) * 4 + ks) * 64 + l) * 8 + e] = h;
    Wfrag[((((size_t)(mat * 2 + 1) * 8 + nt) * 4 + ks) * 64 + l) * 8 + e] = f2bf(lo);
}

// ---- K0c: x -> xh2/xl2 (frag-linear for k1) + w,c scalars ------------------
__global__ __launch_bounds__(256) void k0c_xsplit(const float* __restrict__ x,
        const float* __restrict__ Ww, const float* __restrict__ bw,
        const float* __restrict__ Wc, const float* __restrict__ bc,
        short* __restrict__ xh2, short* __restrict__ xl2,
        float* __restrict__ scal) {
    __shared__ float xs[32][129];
    int rb = blockIdx.x, t = threadIdx.x;
    {
        int r = t >> 3, d0 = (t & 7) * 16;
        const float4* src = (const float4*)(x + (size_t)(rb * 32 + r) * 128 + d0);
#pragma unroll
        for (int q = 0; q < 4; ++q) *(float4*)&xs[r][d0 + q * 4] = src[q];
    }
    __syncthreads();
    int ks = (t >> 5) & 3, rf = t >> 7, l0 = (t & 31) * 2;
    union { bf16x8 v[2]; short s[16]; } hb, lb;
#pragma unroll
    for (int li = 0; li < 2; ++li) {
        int l = l0 + li;
        const float* p = &xs[rf * 16 + (l & 15)][ks * 32 + ((l >> 4) & 3) * 8];
#pragma unroll
        for (int e = 0; e < 8; ++e) {
            float v = p[e];
            short h = f2bf(v);
            hb.s[li * 8 + e] = h;
            lb.s[li * 8 + e] = f2bf(v - bf2f(h));
        }
    }
    {
        short* d1 = xh2 + (size_t)rb * 4096 + (size_t)t * 16;
        short* d2 = xl2 + (size_t)rb * 4096 + (size_t)t * 16;
        *(bf16x8*)d1 = hb.v[0]; *(bf16x8*)(d1 + 8) = hb.v[1];
        *(bf16x8*)d2 = lb.v[0]; *(bf16x8*)(d2 + 8) = lb.v[1];
    }
    // w, c scalars
    int rr = t >> 3, seg = t & 7;
    float pw = 0.f, pc = 0.f;
#pragma unroll
    for (int dq = 0; dq < 16; ++dq) {
        float xv = xs[rr][seg * 16 + dq];
        pw = fmaf(xv, Ww[seg * 16 + dq], pw);
        pc = fmaf(xv, Wc[seg * 16 + dq], pc);
    }
    pw += __shfl_xor(pw, 1); pw += __shfl_xor(pw, 2); pw += __shfl_xor(pw, 4);
    pc += __shfl_xor(pc, 1); pc += __shfl_xor(pc, 2); pc += __shfl_xor(pc, 4);
    if (seg == 0) {
        scal[(size_t)(rb * 32 + rr) * 4 + 0] = fmaxf(pw + bw[0], 0.f);
        scal[(size_t)(rb * 32 + rr) * 4 + 1] = fmaxf(pc + bc[0], 0.f);
    }
}

// ---- K1: q'/m via split-bf16 MFMA (3 products each), fused epilogue --------
__global__ __launch_bounds__(256) void k1_mfma(
    const short* __restrict__ xh2, const short* __restrict__ xl2,
    const short* __restrict__ Wfrag,
    const float* __restrict__ bq, const float* __restrict__ bm,
    float* __restrict__ mq, float* __restrict__ mo, float* __restrict__ scal)
{
    __shared__ __align__(16) short wl[65536];   // 128 KB
    __shared__ float red[32][4][2];
    int t = threadIdx.x, w = t >> 6, l = t & 63;
    int l15 = l & 15, g = l >> 4;
    int row0 = blockIdx.x * 32;
#pragma unroll
    for (int it = 0; it < 32; ++it)
        gload_lds16(Wfrag + (size_t)(it * 256 + t) * 8, wl + (size_t)(it * 256 + w * 64) * 8);
    const short* xb  = xh2 + (size_t)blockIdx.x * 4096;
    const short* xlb = xl2 + (size_t)blockIdx.x * 4096;
    bf16x8 Ah[2][4], Al[2][4];
#pragma unroll
    for (int rf = 0; rf < 2; ++rf)
#pragma unroll
        for (int ks = 0; ks < 4; ++ks) {
            size_t o = ((size_t)(rf * 4 + ks) * 64 + l) * 8;
            Ah[rf][ks] = *(const bf16x8*)(xb + o);
            Al[rf][ks] = *(const bf16x8*)(xlb + o);
        }
    __syncthreads();
    f32x4 accq[2][2] = {}, accm[2][2] = {};
#pragma unroll
    for (int ntp = 0; ntp < 2; ++ntp) {
        int nt = w * 2 + ntp;
#pragma unroll
        for (int ks = 0; ks < 4; ++ks) {
            bf16x8 bhq = *(const bf16x8*)(wl + ((size_t)(0  + nt) * 4 + ks) * 512 + l * 8);
            bf16x8 blq = *(const bf16x8*)(wl + ((size_t)(8  + nt) * 4 + ks) * 512 + l * 8);
            bf16x8 bhm = *(const bf16x8*)(wl + ((size_t)(16 + nt) * 4 + ks) * 512 + l * 8);
            bf16x8 blm = *(const bf16x8*)(wl + ((size_t)(24 + nt) * 4 + ks) * 512 + l * 8);
#pragma unroll
            for (int rf = 0; rf < 2; ++rf) {
                accq[rf][ntp] = __builtin_amdgcn_mfma_f32_16x16x32_bf16(Ah[rf][ks], bhq, accq[rf][ntp], 0, 0, 0);
                accq[rf][ntp] = __builtin_amdgcn_mfma_f32_16x16x32_bf16(Ah[rf][ks], blq, accq[rf][ntp], 0, 0, 0);
                accq[rf][ntp] = __builtin_amdgcn_mfma_f32_16x16x32_bf16(Al[rf][ks], bhq, accq[rf][ntp], 0, 0, 0);
                accm[rf][ntp] = __builtin_amdgcn_mfma_f32_16x16x32_bf16(Ah[rf][ks], bhm, accm[rf][ntp], 0, 0, 0);
                accm[rf][ntp] = __builtin_amdgcn_mfma_f32_16x16x32_bf16(Ah[rf][ks], blm, accm[rf][ntp], 0, 0, 0);
                accm[rf][ntp] = __builtin_amdgcn_mfma_f32_16x16x32_bf16(Al[rf][ks], bhm, accm[rf][ntp], 0, 0, 0);
            }
        }
    }
    float sq1[2][4] = {{0,0,0,0},{0,0,0,0}};
    float sq2[2][4] = {{0,0,0,0},{0,0,0,0}};
#pragma unroll
    for (int ntp = 0; ntp < 2; ++ntp) {
        int c = (w * 2 + ntp) * 16 + l15;
        float bqv = bq[c] + EPSF, bmv = bm[c];
#pragma unroll
        for (int rf = 0; rf < 2; ++rf)
#pragma unroll
            for (int reg = 0; reg < 4; ++reg) {
                int rloc = rf * 16 + g * 4 + reg;
                float qp = accq[rf][ntp][reg] + bqv;
                float mv = 1.0f / (1.0f + expf(-(accm[rf][ntp][reg] + bmv)));
                size_t o = (size_t)(row0 + rloc) * 128 + c;
                mq[o] = mv * qp;
                mo[o] = mv;
                sq1[rf][reg] += qp;
                sq2[rf][reg] += qp * qp;
            }
    }
#pragma unroll
    for (int rf = 0; rf < 2; ++rf)
#pragma unroll
        for (int reg = 0; reg < 4; ++reg) {
            float a = sq1[rf][reg], b = sq2[rf][reg];
            a += __shfl_xor(a, 1); a += __shfl_xor(a, 2);
            a += __shfl_xor(a, 4); a += __shfl_xor(a, 8);
            b += __shfl_xor(b, 1); b += __shfl_xor(b, 2);
            b += __shfl_xor(b, 4); b += __shfl_xor(b, 8);
            if (l15 == 0) {
                red[rf * 16 + g * 4 + reg][w][0] = a;
                red[rf * 16 + g * 4 + reg][w][1] = b;
            }
        }
    __syncthreads();
    if (t < 32) {
        float a = red[t][0][0] + red[t][1][0] + red[t][2][0] + red[t][3][0];
        float b = red[t][0][1] + red[t][1][1] + red[t][2][1] + red[t][3][1];
        scal[(size_t)(row0 + t) * 4 + 2] = a;
        scal[(size_t)(row0 + t) * 4 + 3] = sqrtf(b);
    }
}

// ---- K2: windowed pair loop -> qrh2. One row/block; 4 waves x 4 groups of
//      16 lanes = 16 dists per iteration; lane owns 8 d-elements.
__global__ __launch_bounds__(256) void k2_qr(
    const float* __restrict__ x,
    const float* __restrict__ mq, const float* __restrict__ mo,
    const float* __restrict__ scal, short* __restrict__ qrh2)
{
    int row = blockIdx.x;
    int i = row & (SS - 1);
    const float* xb = x + (size_t)(row - i) * DD;
    int t = threadIdx.x, w = t >> 6, l = t & 63;
    int sub = l >> 4, q = l & 15;
    int qo = q * 8;

    float mqv[8], mov[8];
    {
        const float* mp = mq + (size_t)row * DD + qo;
        float4 a = *(const float4*)mp, b = *(const float4*)(mp + 4);
        mqv[0] = a.x; mqv[1] = a.y; mqv[2] = a.z; mqv[3] = a.w;
        mqv[4] = b.x; mqv[5] = b.y; mqv[6] = b.z; mqv[7] = b.w;
        const float* op = mo + (size_t)row * DD + qo;
        float4 c = *(const float4*)op, d = *(const float4*)(op + 4);
        mov[0] = c.x; mov[1] = c.y; mov[2] = c.z; mov[3] = c.w;
        mov[4] = d.x; mov[5] = d.y; mov[6] = d.z; mov[7] = d.w;
    }
    float wv = scal[row * 4 + 0], cv = scal[row * 4 + 1];
    float sumqp = scal[row * 4 + 2], nb = scal[row * 4 + 3];
    float wi = wv + EPSF;
    float dmaxf = cv + TCUT * wi;
    int dmax = (dmaxf >= (float)i) ? i : (int)dmaxf;

    float acc[8] = {0.f, 0.f, 0.f, 0.f, 0.f, 0.f, 0.f, 0.f};
    int nit = (dmax + 15) >> 4;
    int dbase = 1 + w * 4 + sub;
    for (int it = 0; it < nit; ++it) {
        int dist = dbase + it * 16;
        float xv[8];
        if (dist <= dmax) {
            const float* xp = xb + (size_t)(i - dist) * DD + qo;
            float4 a = *(const float4*)xp, b = *(const float4*)(xp + 4);
            xv[0] = a.x; xv[1] = a.y; xv[2] = a.z; xv[3] = a.w;
            xv[4] = b.x; xv[5] = b.y; xv[6] = b.z; xv[7] = b.w;
        } else {
#pragma unroll
            for (int e = 0; e < 8; ++e) xv[e] = 0.f;
        }
        float t1 = 0.f, s1 = 0.f, s2 = 0.f;
#pragma unroll
        for (int e = 0; e < 8; ++e) {
            float xm = xv[e] * mov[e];
            t1 = fmaf(xv[e], mqv[e], t1);
            s1 += xm;
            s2 = fmaf(xm, xm, s2);
        }
#pragma unroll
        for (int off = 1; off < 16; off <<= 1) {
            t1 += __shfl_xor(t1, off);
            s1 += __shfl_xor(s1, off);
            s2 += __shfl_xor(s2, off);
        }
        float tt = ((float)dist - cv) / wi;
        float pe = 1.0f / coshf(tt);
        float dotv = fmaf(pe, t1, EPSF * sumqp);
        float na = sqrtf(fmaf(pe * pe, s2,
                         fmaf(2.0f * EPSF * pe, s1, (float)DD * EPSF * EPSF)));
        float cosv = fminf(1.0f, fmaxf(-1.0f, dotv / (na * nb)));
        float ang = acosf(cosv);
        float wgt = pe * ang;
#pragma unroll
        for (int e = 0; e < 8; ++e) acc[e] = fmaf(wgt, xv[e], acc[e]);
    }
#pragma unroll
    for (int e = 0; e < 8; ++e) {
        acc[e] += __shfl_xor(acc[e], 16);
        acc[e] += __shfl_xor(acc[e], 32);
    }
    __shared__ float sq[4][DD];
    if (l < 16) {
#pragma unroll
        for (int e = 0; e < 8; ++e) sq[w][qo + e] = acc[e];
    }
    __syncthreads();
    if (t < DD) {
        float v = sq[0][t] + sq[1][t] + sq[2][t] + sq[3][t];
        int rbq = row >> 7, rr = row & 127, rt2 = rr >> 5, lp = rr & 31;
        int k = t;
        qrh2[(((size_t)(rbq * 4 + rt2) * 8 + (k >> 4)) * 64
              + (lp + 32 * ((k >> 3) & 1))) * 8 + (k & 7)] = f2bf(v);
    }
}

// ---- K3: standard GEMM over K=(j,k): C[r,d] = sum A(x*qr) . B(emb) ---------
// grid (rb=128, js=4) = 512 blocks, 256 thr, 4 waves = (dh = w&1, sh = w>>1).
// Block: 64 rows x 128 d x 32 j (K-chunk 4096). Wave: d-pair dh (2 of 4
// 32-d tiles), k-slices sh*4..+4 of each j. A generated in regs (x fold-in);
// B direct global->reg (each frag read once per block; no LDS, NO BARRIERS
// in main loop, no acc-zeroing, no epilogue in loop). sh-halves combined via
// LDS once at end -> 4 f32 planes.
__global__ __launch_bounds__(256, 2) void k3_gemm(
    const float* __restrict__ x, const short* __restrict__ embB,
    const short* __restrict__ qrh2, float* __restrict__ part)
{
    __shared__ float xt[32][68];     // [j][r], padded
    __shared__ float sof[64][128];   // 32 KB combine/writeout buffer
    int t = threadIdx.x, w = t >> 6, l = t & 63;
    int l31 = l & 31, hi = l >> 5;
    int dh = w & 1, sh = w >> 1;
    int rb = blockIdx.x, js = blockIdx.y;

    // stage xt[j][r] = x[(rb*64+r)*128 + js*32 + j]
    {
        int r = t >> 2, q = t & 3;
        const float* xp = x + (size_t)(rb * 64 + r) * 128 + js * 32 + q * 8;
        float4 a = *(const float4*)xp, b = *(const float4*)(xp + 4);
        xt[q * 8 + 0][r] = a.x; xt[q * 8 + 1][r] = a.y;
        xt[q * 8 + 2][r] = a.z; xt[q * 8 + 3][r] = a.w;
        xt[q * 8 + 4][r] = b.x; xt[q * 8 + 5][r] = b.y;
        xt[q * 8 + 6][r] = b.z; xt[q * 8 + 7][r] = b.w;
    }

    // qr A-base fragments: 2 rt x own 4 k-slices (packed u32x4 each)
    unsigned int qrp[2][4][4];
#pragma unroll
    for (int rt = 0; rt < 2; ++rt) {
        int R32 = rb * 2 + rt;
#pragma unroll
        for (int s = 0; s < 4; ++s) {
            union { bf16x8 v; unsigned int u[4]; } qb;
            qb.v = *(const bf16x8*)(qrh2
                + (((size_t)R32 * 8 + sh * 4 + s) * 64 + l) * 8);
#pragma unroll
            for (int p = 0; p < 4; ++p) qrp[rt][s][p] = qb.u[p];
        }
    }

    const short* Bbase = embB + (size_t)(js * 32) * 16384
                         + (size_t)(dh * 2) * 4096 + (size_t)(sh * 4) * 512
                         + (size_t)l * 8;

    f32x16 acc[2][2];
#pragma unroll
    for (int rt = 0; rt < 2; ++rt)
#pragma unroll
        for (int i = 0; i < 2; ++i)
#pragma unroll
            for (int q = 0; q < 16; ++q) acc[rt][i][q] = 0.f;

#define LOADB(BN, JJ)                                                       \
    {                                                                       \
        const short* bp_ = Bbase + (size_t)(JJ) * 16384;                    \
        _Pragma("unroll")                                                   \
        for (int i = 0; i < 2; ++i)                                         \
            _Pragma("unroll")                                               \
            for (int s = 0; s < 4; ++s)                                     \
                BN[i][s] = *(const bf16x8*)(bp_ + i * 4096 + s * 512);      \
    }

#define COMPUTE(BN, JJ)                                                     \
    {                                                                       \
        float xs0 = xt[JJ][l31], xs1 = xt[JJ][32 + l31];                    \
        _Pragma("unroll")                                                   \
        for (int s = 0; s < 4; ++s) {                                       \
            union { bf16x8 v; unsigned int u[4]; } a0, a1;                  \
            _Pragma("unroll")                                               \
            for (int p = 0; p < 4; ++p) {                                   \
                unsigned int q0 = qrp[0][s][p], q1 = qrp[1][s][p];          \
                a0.u[p] = pack_bf16(u2f(q0 << 16) * xs0,                    \
                                    u2f(q0 & 0xFFFF0000u) * xs0);           \
                a1.u[p] = pack_bf16(u2f(q1 << 16) * xs1,                    \
                                    u2f(q1 & 0xFFFF0000u) * xs1);           \
            }                                                               \
            acc[0][0] = __builtin_amdgcn_mfma_f32_32x32x16_bf16(            \
                a0.v, BN[0][s], acc[0][0], 0, 0, 0);                        \
            acc[0][1] = __builtin_amdgcn_mfma_f32_32x32x16_bf16(            \
                a0.v, BN[1][s], acc[0][1], 0, 0, 0);                        \
            acc[1][0] = __builtin_amdgcn_mfma_f32_32x32x16_bf16(            \
                a1.v, BN[0][s], acc[1][0], 0, 0, 0);                        \
            acc[1][1] = __builtin_amdgcn_mfma_f32_32x32x16_bf16(            \
                a1.v, BN[1][s], acc[1][1], 0, 0, 0);                        \
        }                                                                   \
    }

    bf16x8 B0[2][4], B1[2][4];
    LOADB(B0, 0)
    __syncthreads();   // xt visible

#pragma unroll 1
    for (int jj = 0; jj < 32; jj += 2) {
        if (jj + 1 < 32) LOADB(B1, jj + 1)
        COMPUTE(B0, jj)
        if (jj + 2 < 32) LOADB(B0, jj + 2)
        COMPUTE(B1, jj + 1)
    }
#undef LOADB
#undef COMPUTE

    // combine sh-halves via LDS, then coalesced writeout
    __syncthreads();
    if (sh == 0) {
#pragma unroll
        for (int rt = 0; rt < 2; ++rt)
#pragma unroll
            for (int i = 0; i < 2; ++i)
#pragma unroll
                for (int q = 0; q < 16; ++q) {
                    int r = rt * 32 + (q & 3) + 8 * (q >> 2) + 4 * hi;
                    sof[r][(dh * 2 + i) * 32 + l31] = acc[rt][i][q];
                }
    }
    __syncthreads();
    if (sh == 1) {
#pragma unroll
        for (int rt = 0; rt < 2; ++rt)
#pragma unroll
            for (int i = 0; i < 2; ++i)
#pragma unroll
                for (int q = 0; q < 16; ++q) {
                    int r = rt * 32 + (q & 3) + 8 * (q >> 2) + 4 * hi;
                    sof[r][(dh * 2 + i) * 32 + l31] += acc[rt][i][q];
                }
    }
    __syncthreads();
#pragma unroll
    for (int i = 0; i < 8; ++i) {
        int idx = i * 256 + t;
        int r = idx >> 5, c4 = (idx & 31) * 4;
        float4 v = *(const float4*)&sof[r][c4];
        *(float4*)(part + (size_t)js * (NROWS * DD)
                   + (size_t)(rb * 64 + r) * 128 + c4) = v;
    }
}

// ---- K4: sum 4 f32 partials + x, LayerNorm ---------------------------------
__global__ __launch_bounds__(256) void k4_ln(
    const float* __restrict__ x, const float* __restrict__ part,
    const float* __restrict__ gamma, const float* __restrict__ beta,
    float* __restrict__ out)
{
    int wave = threadIdx.x >> 6, lane = threadIdx.x & 63;
    int row = blockIdx.x * 4 + wave;
    size_t base = (size_t)row * DD;
    float r0 = x[base + lane], r1 = x[base + lane + 64];
#pragma unroll
    for (int p = 0; p < 4; ++p) {
        r0 += part[(size_t)p * NROWS * DD + base + lane];
        r1 += part[(size_t)p * NROWS * DD + base + lane + 64];
    }
    float s = r0 + r1, s2 = r0 * r0 + r1 * r1;
#pragma unroll
    for (int off = 32; off > 0; off >>= 1) {
        s += __shfl_xor(s, off);
        s2 += __shfl_xor(s2, off);
    }
    float mu = s * (1.0f / DD);
    float var = s2 * (1.0f / DD) - mu * mu;
    var = fmaxf(var, 0.0f);
    float rs = rsqrtf(var + LN_EPSF);
    out[base + lane] = (r0 - mu) * rs * gamma[lane] + beta[lane];
    out[base + lane + 64] = (r1 - mu) * rs * gamma[lane + 64] + beta[lane + 64];
}

extern "C" void kernel_launch(void* const* d_in, const int* in_sizes, int n_in,
                              void* d_out, int out_size, void* d_ws, size_t ws_size,
                              hipStream_t stream) {
    const float* x     = (const float*)d_in[0];
    const float* Wq    = (const float*)d_in[1];
    const float* bq    = (const float*)d_in[2];
    const float* Wm    = (const float*)d_in[3];
    const float* bm    = (const float*)d_in[4];
    const float* Ww    = (const float*)d_in[5];
    const float* bw    = (const float*)d_in[6];
    const float* Wc    = (const float*)d_in[7];
    const float* bc    = (const float*)d_in[8];
    const float* emb   = (const float*)d_in[9];
    const float* gamma = (const float*)d_in[10];
    const float* beta  = (const float*)d_in[11];
    float* out = (float*)d_out;
    float* ws  = (float*)d_ws;

    short* embB  = (short*)ws;                  // 4 MB
    short* qrh2  = (short*)(ws + 1048576);      // 2 MB
    float* scal  = ws + 1572864;
    float* part  = ws + 1605632;                // 16 MB (4 f32 planes)
    float* tr    = ws + 1605632;                // transients alias part
    short* xh2   = (short*)tr;
    short* xl2   = (short*)(tr + 524288);
    float* mq    = tr + 1048576;
    float* mo    = tr + 2097152;
    short* Wfrag = (short*)(tr + 3145728);

    hipLaunchKernelGGL(k0a_emb,   dim3(128),    dim3(256), 0, stream, emb, embB);
    hipLaunchKernelGGL(k0w_split, dim3(256),    dim3(256), 0, stream, Wq, Wm, Wfrag);
    hipLaunchKernelGGL(k0c_xsplit,dim3(256),    dim3(256), 0, stream,
                       x, Ww, bw, Wc, bc, xh2, xl2, scal);
    hipLaunchKernelGGL(k1_mfma,   dim3(256),    dim3(256), 0, stream,
                       xh2, xl2, Wfrag, bq, bm, mq, mo, scal);
    hipLaunchKernelGGL(k2_qr,     dim3(8192),   dim3(256), 0, stream,
                       x, mq, mo, scal, qrh2);
    hipLaunchKernelGGL(k3_gemm,   dim3(128, 4), dim3(256), 0, stream,
                       x, embB, qrh2, part);
    hipLaunchKernelGGL(k4_ln,     dim3(2048),   dim3(256), 0, stream,
                       x, part, gamma, beta, out);
}